// Round 4
// baseline (197.086 us; speedup 1.0000x reference)
//
#include <hip/hip_runtime.h>

#define BQ 8
#define NQ 2048
#define ROWS 4      // i-rows per block (small burst, high occupancy)
#define TPB 256
#define NBLK (BQ * (NQ / ROWS))   // 4096 blocks
#define JTILE (TPB * 4)           // j covered per sweep: 1024
#define NJT (NQ / JTILE)          // 2 sweeps

typedef float f32x4 __attribute__((ext_vector_type(4)));   // native vec for nontemporal builtin

__global__ __launch_bounds__(TPB, 8) void idla_main(
        const float* __restrict__ preds,
        const float* __restrict__ targets,
        const float* __restrict__ adj,
        float2* __restrict__ partials) {
    // No LDS point staging (points are L2-resident); LDS only for wave partials.
    // launch_bounds(256,8): force VGPR<=64 -> 8 waves/SIMD = 32 waves/CU.
    __shared__ float red_sq[TPB / 64], red_ad[TPB / 64];

    const int nb_per_batch = NQ / ROWS;               // 512
    const int b  = blockIdx.x / nb_per_batch;
    const int i0 = (blockIdx.x % nb_per_batch) * ROWS;
    const int tid = threadIdx.x;

    const float* pb   = preds   + (size_t)b * NQ * 3;
    const float* tb   = targets + (size_t)b * NQ * 3;
    const float* adjb = adj     + (size_t)b * NQ * NQ;

    float acc_sq = 0.0f;   // sum of ((dp - dt) * a)^2
    float acc_ad = 0.0f;   // sum of a

    #pragma unroll
    for (int jt = 0; jt < NJT; ++jt) {
        const int j0 = jt * JTILE + tid * 4;
        // 4 consecutive j-points = 12 contiguous floats = 3x float4 (L2-hit).
        const float4* pj = (const float4*)(pb + 3 * j0);
        const float4* tj = (const float4*)(tb + 3 * j0);
        float4 f0 = pj[0], f1 = pj[1], f2 = pj[2];
        float4 g0 = tj[0], g1 = tj[1], g2 = tj[2];

        // Adj rows: stream-once -> nontemporal (nt), don't pollute L2.
        f32x4 a4[ROWS];
        #pragma unroll
        for (int r = 0; r < ROWS; ++r)
            a4[r] = __builtin_nontemporal_load(
                        (const f32x4*)&adjb[(size_t)(i0 + r) * NQ + j0]);

        float jx[4] = {f0.x, f0.w, f1.z, f2.y};
        float jy[4] = {f0.y, f1.x, f1.w, f2.z};
        float jz[4] = {f0.z, f1.y, f2.x, f2.w};
        float ux[4] = {g0.x, g0.w, g1.z, g2.y};
        float uy[4] = {g0.y, g1.x, g1.w, g2.z};
        float uz[4] = {g0.z, g1.y, g2.x, g2.w};

        #pragma unroll
        for (int r = 0; r < ROWS; ++r) {
            // i-point coords: block-uniform addresses -> scalar s_loads (L2-hit).
            const int i = i0 + r;
            const float pix = pb[3*i], piy = pb[3*i+1], piz = pb[3*i+2];
            const float tix = tb[3*i], tiy = tb[3*i+1], tiz = tb[3*i+2];
            float av[4] = {a4[r][0], a4[r][1], a4[r][2], a4[r][3]};
            #pragma unroll
            for (int jj = 0; jj < 4; ++jj) {
                float dx = pix - jx[jj];
                float dy = piy - jy[jj];
                float dz = piz - jz[jj];
                float sp = fmaf(dx, dx, fmaf(dy, dy, dz * dz)); // dp^2
                float ex = tix - ux[jj];
                float ey = tiy - uy[jj];
                float ez = tiz - uz[jj];
                float st = fmaf(ex, ex, fmaf(ey, ey, ez * ez)); // dt^2
                // (dp - dt)^2 = sp + st - 2*sqrt(sp*st): ONE v_sqrt_f32
                float rt = __builtin_amdgcn_sqrtf(sp * st);
                float t  = fmaf(-2.0f, rt, sp + st);
                float aa = av[jj] * av[jj];
                acc_sq = fmaf(t, aa, acc_sq);
                acc_ad += av[jj];
            }
        }
    }

    // Wave64 shuffle reduction
    #pragma unroll
    for (int off = 32; off > 0; off >>= 1) {
        acc_sq += __shfl_down(acc_sq, off, 64);
        acc_ad += __shfl_down(acc_ad, off, 64);
    }
    const int wave = tid >> 6;
    if ((tid & 63) == 0) { red_sq[wave] = acc_sq; red_ad[wave] = acc_ad; }
    __syncthreads();
    if (tid == 0) {
        float s_sq = 0.0f, s_ad = 0.0f;
        #pragma unroll
        for (int w = 0; w < TPB / 64; w++) { s_sq += red_sq[w]; s_ad += red_ad[w]; }
        partials[blockIdx.x] = make_float2(s_sq, s_ad);
    }
}

__global__ __launch_bounds__(256) void idla_reduce(
        const float2* __restrict__ partials, float* __restrict__ out) {
    double s = 0.0, a = 0.0;
    for (int i = threadIdx.x; i < NBLK; i += 256) {
        float2 p = partials[i];
        s += (double)p.x;
        a += (double)p.y;
    }
    #pragma unroll
    for (int off = 32; off > 0; off >>= 1) {
        s += __shfl_down(s, off, 64);
        a += __shfl_down(a, off, 64);
    }
    __shared__ double rs[4], ra[4];
    const int wave = threadIdx.x >> 6;
    if ((threadIdx.x & 63) == 0) { rs[wave] = s; ra[wave] = a; }
    __syncthreads();
    if (threadIdx.x == 0) {
        double ts = rs[0] + rs[1] + rs[2] + rs[3];
        double ta = ra[0] + ra[1] + ra[2] + ra[3];
        out[0] = (float)(ts / ta);
    }
}

extern "C" void kernel_launch(void* const* d_in, const int* in_sizes, int n_in,
                              void* d_out, int out_size, void* d_ws, size_t ws_size,
                              hipStream_t stream) {
    const float* preds   = (const float*)d_in[0];
    const float* targets = (const float*)d_in[1];
    const float* adj     = (const float*)d_in[2];
    float2* partials = (float2*)d_ws;   // NBLK * 8 B = 32 KB of workspace
    float*  out      = (float*)d_out;

    hipLaunchKernelGGL(idla_main, dim3(NBLK), dim3(TPB), 0, stream,
                       preds, targets, adj, partials);
    hipLaunchKernelGGL(idla_reduce, dim3(1), dim3(256), 0, stream, partials, out);
}

// Round 6
// 188.081 us; speedup vs baseline: 1.0479x; 1.0479x over previous
//
#include <hip/hip_runtime.h>

#define BQ 8
#define NQ 2048
#define TPB 256
#define JTILE (TPB * 4)           // j-columns per block: 1024
#define NJT (NQ / JTILE)          // 2 j-tiles
#define ICHUNK 16                 // i-rows per block
#define NIC (NQ / ICHUNK)         // 128 i-chunks
#define NBLK (BQ * NJT * NIC)     // 2048 blocks

typedef float f32x4 __attribute__((ext_vector_type(4)));

// 4 nontemporal adj row-loads (1 KB/wave each), rows rbase..rbase+3
#define LOAD4(buf, rbase)                                                     \
    do {                                                                      \
        _Pragma("unroll")                                                     \
        for (int r = 0; r < 4; ++r)                                           \
            buf[r] = __builtin_nontemporal_load(                              \
                (const f32x4*)(arow + (size_t)((rbase) + r) * NQ));           \
    } while (0)

// compute 4 rows x 4 j against register-resident j-points
#define COMP4(buf, rbase)                                                     \
    do {                                                                      \
        _Pragma("unroll")                                                     \
        for (int r = 0; r < 4; ++r) {                                         \
            const int i = (rbase) + r;    /* block-uniform -> s_loads */      \
            const float pix = pb[3*i], piy = pb[3*i+1], piz = pb[3*i+2];      \
            const float tix = tb[3*i], tiy = tb[3*i+1], tiz = tb[3*i+2];      \
            _Pragma("unroll")                                                 \
            for (int jj = 0; jj < 4; ++jj) {                                  \
                float dx = pix - jx[jj];                                      \
                float dy = piy - jy[jj];                                      \
                float dz = piz - jz[jj];                                      \
                float sp = fmaf(dx, dx, fmaf(dy, dy, dz * dz));               \
                float ex = tix - ux[jj];                                      \
                float ey = tiy - uy[jj];                                      \
                float ez = tiz - uz[jj];                                      \
                float st = fmaf(ex, ex, fmaf(ey, ey, ez * ez));               \
                float rt = __builtin_amdgcn_sqrtf(sp * st);                   \
                float t  = fmaf(-2.0f, rt, sp + st);                          \
                float av = buf[r][jj];                                        \
                float aa = av * av;                                           \
                acc_sq = fmaf(t, aa, acc_sq);                                 \
                acc_ad += av;                                                 \
            }                                                                 \
        }                                                                     \
    } while (0)

__global__ __launch_bounds__(TPB, 4) void idla_main(
        const float* __restrict__ preds,
        const float* __restrict__ targets,
        const float* __restrict__ adj,
        float2* __restrict__ partials) {
    __shared__ float red_sq[TPB / 64], red_ad[TPB / 64];

    const int blk = blockIdx.x;
    const int b   = blk / (NJT * NIC);
    const int rem = blk % (NJT * NIC);
    const int jt  = rem / NIC;
    const int ic  = rem % NIC;
    const int i0  = ic * ICHUNK;
    const int tid = threadIdx.x;
    const int j0  = jt * JTILE + tid * 4;

    const float* pb   = preds   + (size_t)b * NQ * 3;
    const float* tb   = targets + (size_t)b * NQ * 3;
    const float* arow = adj + (size_t)b * NQ * NQ + j0;   // per-lane column base

    // j-points: loaded ONCE per block into registers (3+3 coalesced float4).
    const float4* pj = (const float4*)(pb + 3 * j0);
    const float4* tj = (const float4*)(tb + 3 * j0);
    float4 f0 = pj[0], f1 = pj[1], f2 = pj[2];
    float4 g0 = tj[0], g1 = tj[1], g2 = tj[2];
    float jx[4] = {f0.x, f0.w, f1.z, f2.y};
    float jy[4] = {f0.y, f1.x, f1.w, f2.z};
    float jz[4] = {f0.z, f1.y, f2.x, f2.w};
    float ux[4] = {g0.x, g0.w, g1.z, g2.y};
    float uy[4] = {g0.y, g1.x, g1.w, g2.z};
    float uz[4] = {g0.z, g1.y, g2.x, g2.w};

    float acc_sq = 0.0f;
    float acc_ad = 0.0f;

    // Software-pipelined adj stream over 4 groups of 4 rows:
    // next group's 4 KB is in flight under the current group's compute.
    f32x4 bufA[4], bufB[4];
    LOAD4(bufA, i0);
    LOAD4(bufB, i0 + 4);
    COMP4(bufA, i0);
    LOAD4(bufA, i0 + 8);
    COMP4(bufB, i0 + 4);
    LOAD4(bufB, i0 + 12);
    COMP4(bufA, i0 + 8);
    COMP4(bufB, i0 + 12);

    // Wave64 shuffle reduction
    #pragma unroll
    for (int off = 32; off > 0; off >>= 1) {
        acc_sq += __shfl_down(acc_sq, off, 64);
        acc_ad += __shfl_down(acc_ad, off, 64);
    }
    const int wave = tid >> 6;
    if ((tid & 63) == 0) { red_sq[wave] = acc_sq; red_ad[wave] = acc_ad; }
    __syncthreads();
    if (tid == 0) {
        float s_sq = 0.0f, s_ad = 0.0f;
        #pragma unroll
        for (int w = 0; w < TPB / 64; w++) { s_sq += red_sq[w]; s_ad += red_ad[w]; }
        partials[blockIdx.x] = make_float2(s_sq, s_ad);
    }
}

__global__ __launch_bounds__(256) void idla_reduce(
        const float2* __restrict__ partials, float* __restrict__ out) {
    double s = 0.0, a = 0.0;
    for (int i = threadIdx.x; i < NBLK; i += 256) {
        float2 p = partials[i];
        s += (double)p.x;
        a += (double)p.y;
    }
    #pragma unroll
    for (int off = 32; off > 0; off >>= 1) {
        s += __shfl_down(s, off, 64);
        a += __shfl_down(a, off, 64);
    }
    __shared__ double rs[4], ra[4];
    const int wave = threadIdx.x >> 6;
    if ((threadIdx.x & 63) == 0) { rs[wave] = s; ra[wave] = a; }
    __syncthreads();
    if (threadIdx.x == 0) {
        double ts = rs[0] + rs[1] + rs[2] + rs[3];
        double ta = ra[0] + ra[1] + ra[2] + ra[3];
        out[0] = (float)(ts / ta);
    }
}

extern "C" void kernel_launch(void* const* d_in, const int* in_sizes, int n_in,
                              void* d_out, int out_size, void* d_ws, size_t ws_size,
                              hipStream_t stream) {
    const float* preds   = (const float*)d_in[0];
    const float* targets = (const float*)d_in[1];
    const float* adj     = (const float*)d_in[2];
    float2* partials = (float2*)d_ws;   // NBLK * 8 B = 16 KB of workspace
    float*  out      = (float*)d_out;

    hipLaunchKernelGGL(idla_main, dim3(NBLK), dim3(TPB), 0, stream,
                       preds, targets, adj, partials);
    hipLaunchKernelGGL(idla_reduce, dim3(1), dim3(256), 0, stream, partials, out);
}